// Round 3
// baseline (1184.952 us; speedup 1.0000x reference)
//
#include <hip/hip_runtime.h>
#include <math.h>

#define PI_F 3.14159265358979f
#define HH 384
#define WW 384
#define WF 193
#define CIN 16
#define MM 32
#define KK 64
#define BB 8
#define NSAMP (CIN*HH*WW)

typedef float2 cfloat;

__device__ __forceinline__ int bitrev6(int x) {
  return ((x & 1) << 5) | ((x & 2) << 3) | ((x & 4) << 1) |
         ((x & 8) >> 1) | ((x & 16) >> 3) | ((x & 32) >> 5);
}

// Fill tw[j] = (cos(2*pi*j/384), sin(2*pi*j/384)), computed in double so the
// fp32 values are correctly rounded.
__global__ void k_tw(float2* __restrict__ tw) {
  int j = blockIdx.x * 64 + threadIdx.x;
  if (j < 384) {
    double a = (double)j * (6.283185307179586476925286766559 / 384.0);
    tw[j] = make_float2((float)cos(a), (float)sin(a));
  }
}

// In-wave 384-point complex FFT. Input: reg n1 of lane l = x[n1 + 6*l].
// Output: reg k1 of lane l = X[bitrev6(l) + 64*k1].  SIGN=-1 fwd, +1 inv (unscaled).
template<int SIGN>
__device__ __forceinline__ void fft384_regs(float zr[6], float zi[6], int lane,
                                            const float2* __restrict__ tw) {
  #pragma unroll
  for (int L = 64; L >= 2; L >>= 1) {
    const int d = L >> 1;
    const int stride = 384 / L;
    const bool up = (lane & d) != 0;
    const int tt = lane & (d - 1);
    float2 t = tw[tt * stride];
    const float c = t.x, s = (float)SIGN * t.y;
    #pragma unroll
    for (int n1 = 0; n1 < 6; ++n1) {
      float orr = __shfl_xor(zr[n1], d, 64);
      float oii = __shfl_xor(zi[n1], d, 64);
      if (up) {
        float ur = orr - zr[n1], ui = oii - zi[n1];
        zr[n1] = ur * c - ui * s;
        zi[n1] = ur * s + ui * c;
      } else {
        zr[n1] += orr;
        zi[n1] += oii;
      }
    }
  }
  const int k2 = bitrev6(lane);
  #pragma unroll
  for (int n1 = 1; n1 < 6; ++n1) {
    float2 t = tw[k2 * n1];  // k2*n1 <= 63*5 = 315 < 384
    const float c = t.x, s = (float)SIGN * t.y;
    float tr = zr[n1] * c - zi[n1] * s;
    float ti = zr[n1] * s + zi[n1] * c;
    zr[n1] = tr; zi[n1] = ti;
  }
  const float s3 = (float)SIGN * 0.86602540378443864676f;
  float E[6], O[6];
  {
    float sr = zr[2] + zr[4], si = zi[2] + zi[4];
    float dr = zr[2] - zr[4], di = zi[2] - zi[4];
    E[0] = zr[0] + sr; E[1] = zi[0] + si;
    float mr = zr[0] - 0.5f * sr, mi = zi[0] - 0.5f * si;
    E[2] = mr - s3 * di; E[3] = mi + s3 * dr;
    E[4] = mr + s3 * di; E[5] = mi - s3 * dr;
  }
  {
    float sr = zr[3] + zr[5], si = zi[3] + zi[5];
    float dr = zr[3] - zr[5], di = zi[3] - zi[5];
    O[0] = zr[1] + sr; O[1] = zi[1] + si;
    float mr = zr[1] - 0.5f * sr, mi = zi[1] - 0.5f * si;
    O[2] = mr - s3 * di; O[3] = mi + s3 * dr;
    O[4] = mr + s3 * di; O[5] = mi - s3 * dr;
  }
  float t1r = 0.5f * O[2] - s3 * O[3], t1i = 0.5f * O[3] + s3 * O[2];
  float t2r = -0.5f * O[4] - s3 * O[5], t2i = -0.5f * O[5] + s3 * O[4];
  zr[0] = E[0] + O[0]; zi[0] = E[1] + O[1];
  zr[3] = E[0] - O[0]; zi[3] = E[1] - O[1];
  zr[1] = E[2] + t1r;  zi[1] = E[3] + t1i;
  zr[4] = E[2] - t1r;  zi[4] = E[3] - t1i;
  zr[2] = E[4] + t2r;  zi[2] = E[5] + t2i;
  zr[5] = E[4] - t2r;  zi[5] = E[5] - t2i;
}

__global__ void k0_zero(float* sums) {
  if (threadIdx.x < 16) sums[threadIdx.x] = 0.f;
}

__global__ __launch_bounds__(256) void k1_reduce(const float* __restrict__ x,
                                                 float* __restrict__ sums) {
  int b = blockIdx.x >> 7;
  int slice = blockIdx.x & 127;
  const float4* p = (const float4*)(x + (size_t)b * NSAMP) + (size_t)slice * 4608;
  float s = 0.f, q = 0.f;
  for (int i = threadIdx.x; i < 4608; i += 256) {
    float4 v = p[i];
    s += v.x + v.y + v.z + v.w;
    q += v.x*v.x + v.y*v.y + v.z*v.z + v.w*v.w;
  }
  #pragma unroll
  for (int o = 32; o; o >>= 1) { s += __shfl_down(s, o, 64); q += __shfl_down(q, o, 64); }
  __shared__ float ls[4], lq[4];
  int wv = threadIdx.x >> 6;
  if ((threadIdx.x & 63) == 0) { ls[wv] = s; lq[wv] = q; }
  __syncthreads();
  if (threadIdx.x == 0) {
    s = ls[0] + ls[1] + ls[2] + ls[3];
    q = lq[0] + lq[1] + lq[2] + lq[3];
    atomicAdd(&sums[b], s);
    atomicAdd(&sums[8 + b], q);
  }
}

// Row real-FFT: two real rows packed as one complex FFT, unpacked by symmetry.
__global__ __launch_bounds__(256) void k2_rowfft(const float* __restrict__ x,
                                                 const float* __restrict__ sums,
                                                 const float2* __restrict__ twg,
                                                 cfloat* __restrict__ S1) {
  __shared__ float zre[4][384], zim[4][384];
  __shared__ float2 twl[384];
  int wv = threadIdx.x >> 6, lane = threadIdx.x & 63;
  for (int i = threadIdx.x; i < 384; i += 256) twl[i] = twg[i];
  int pairIdx = blockIdx.x * 4 + wv;
  int bc = pairIdx / 192, p = pairIdx % 192;
  int b = bc >> 4;
  float mean = sums[b] * (1.0f / (float)NSAMP);
  float var = sums[8 + b] * (1.0f / (float)NSAMP) - mean * mean;
  float istd = rsqrtf(var + 1e-5f);
  const float* rowA = x + (size_t)bc * (HH * WW) + (size_t)(2 * p) * WW;
  const float* rowB = rowA + WW;
  #pragma unroll
  for (int i = 0; i < 6; ++i) {
    int n = lane + 64 * i;
    zre[wv][n] = (rowA[n] - mean) * istd;
    zim[wv][n] = (rowB[n] - mean) * istd;
  }
  __syncthreads();
  float ar[6], ai[6];
  #pragma unroll
  for (int n1 = 0; n1 < 6; ++n1) {
    ar[n1] = zre[wv][6 * lane + n1];
    ai[n1] = zim[wv][6 * lane + n1];
  }
  fft384_regs<-1>(ar, ai, lane, twl);
  int k2 = bitrev6(lane);
  #pragma unroll
  for (int k1 = 0; k1 < 6; ++k1) {
    zre[wv][k2 + 64 * k1] = ar[k1];
    zim[wv][k2 + 64 * k1] = ai[k1];
  }
  __syncthreads();
  cfloat* outA = S1 + (size_t)bc * (HH * WF) + (size_t)(2 * p) * WF;
  cfloat* outB = outA + WF;
  #pragma unroll
  for (int j = 0; j < 4; ++j) {
    int k = lane + 64 * j;
    if (k < WF) {
      int km = (k == 0) ? 0 : (384 - k);
      float zr1 = zre[wv][k], zi1 = zim[wv][k];
      float zr2 = zre[wv][km], zi2 = zim[wv][km];
      outA[k] = make_float2(0.5f * (zr1 + zr2), 0.5f * (zi1 - zi2));
      outB[k] = make_float2(0.5f * (zi1 + zi2), 0.5f * (zr2 - zr1));
    }
  }
}

// In-place column FFT over h, fused transpose through LDS (8 columns per block).
template<int SIGN>
__global__ __launch_bounds__(512) void k3_colfft(cfloat* __restrict__ data,
                                                 const float2* __restrict__ twg,
                                                 float scale) {
  __shared__ float re[384 * 9], im[384 * 9];  // pad 8->9 to break bank conflicts
  __shared__ float2 twl[384];
  int bc = blockIdx.x / 25, tile = blockIdx.x % 25;
  int w0 = tile * 8;
  cfloat* base = data + (size_t)bc * (HH * WF);
  int tid = threadIdx.x;
  if (tid < 384) twl[tid] = twg[tid];
  #pragma unroll
  for (int i = 0; i < 6; ++i) {
    int idx = tid + 512 * i;
    int h = idx >> 3, j = idx & 7;
    int w = w0 + j;
    if (w < WF) {
      cfloat v = base[(size_t)h * WF + w];
      re[h * 9 + j] = v.x;
      im[h * 9 + j] = v.y;
    }
  }
  __syncthreads();
  int wv = tid >> 6, lane = tid & 63;
  int w = w0 + wv;
  if (w < WF) {
    float ar[6], ai[6];
    #pragma unroll
    for (int n1 = 0; n1 < 6; ++n1) {
      int h = 6 * lane + n1;
      ar[n1] = re[h * 9 + wv];
      ai[n1] = im[h * 9 + wv];
    }
    fft384_regs<SIGN>(ar, ai, lane, twl);
    int k2 = bitrev6(lane);
    #pragma unroll
    for (int k1 = 0; k1 < 6; ++k1) {
      int h = k2 + 64 * k1;
      re[h * 9 + wv] = ar[k1] * scale;
      im[h * 9 + wv] = ai[k1] * scale;
    }
  }
  __syncthreads();
  #pragma unroll
  for (int i = 0; i < 6; ++i) {
    int idx = tid + 512 * i;
    int h = idx >> 3, j = idx & 7;
    int w2 = w0 + j;
    if (w2 < WF) {
      base[(size_t)h * WF + w2] = make_float2(re[h * 9 + j], im[h * 9 + j]);
    }
  }
}

// Mode mixing: Yf[b,k,h,w] = sum_m C[k,m] * T[m,h,w] * sum_c B[m,c] * Xf[b,c,h,w]
__global__ __launch_bounds__(256) void k4_mix(
    const cfloat* __restrict__ S1, cfloat* __restrict__ Yf,
    const float* __restrict__ theta, const float* __restrict__ B_re,
    const float* __restrict__ B_im, const float* __restrict__ C_re,
    const float* __restrict__ C_im, const float* __restrict__ alpha_raw,
    const float* __restrict__ beta, const float* __restrict__ log_dc,
    const float* __restrict__ log_tau, const float* __restrict__ log_scale,
    const float* __restrict__ log_bw) {
  __shared__ float2 Xs[CIN * 97];
  __shared__ float2 Zs[MM * 97];
  __shared__ float2 Bt[CIN * MM];   // [c][m]
  __shared__ float2 Ct[MM * KK];    // [m][k]
  int b = blockIdx.x / HH, h = blockIdx.x % HH;
  int t = threadIdx.x;
  for (int idx = t; idx < CIN * MM; idx += 256) {
    int c = idx >> 5, m = idx & 31;
    Bt[idx] = make_float2(B_re[m * CIN + c], B_im[m * CIN + c]);
  }
  for (int idx = t; idx < MM * KK; idx += 256) {
    int m = idx >> 6, k = idx & 63;
    Ct[idx] = make_float2(C_re[k * MM + m], C_im[k * MM + m]);
  }
  // per-thread mode params (accurate transcendentals, once/thread)
  int m_ = t & 31;
  float sth, cth;
  sincosf(theta[m_], &sth, &cth);
  float bet = beta[m_];
  float araw = alpha_raw[m_];
  float sp = (araw > 20.f) ? araw : log1pf(expf(araw));
  float s_m = expf(log_scale[m_]);
  float tau_m = expf(log_tau[m_]);
  float dc_m = expf(log_dc[m_]);
  float wc8i = expf(-8.f * log_bw[m_]);
  int hs = (h < 192) ? h : h - 384;
  float oy = (2.f * PI_F / 384.f) * (float)hs;

  for (int half = 0; half < 2; ++half) {
    const int wbase = half ? 97 : 0;
    const int cnt = half ? 96 : 97;
    __syncthreads();
    for (int idx = t; idx < CIN * cnt; idx += 256) {
      int c = idx / cnt, wo = idx - c * cnt;
      Xs[c * 97 + wo] = S1[((size_t)(b * CIN + c) * HH + h) * WF + wbase + wo];
    }
    __syncthreads();
    // Z phase: thread (m = t&31, w strided by 8)
    {
      int w0i = t >> 5;
      for (int wo = w0i; wo < cnt; wo += 8) {
        float zr = 0.f, zi = 0.f;
        #pragma unroll
        for (int c = 0; c < CIN; ++c) {
          float2 Xv = Xs[c * 97 + wo];
          float2 Bv = Bt[c * MM + m_];
          zr += Bv.x * Xv.x - Bv.y * Xv.y;
          zi += Bv.x * Xv.y + Bv.y * Xv.x;
        }
        float ox = (2.f * PI_F / 384.f) * (float)(wbase + wo);
        float vdw = cth * ox + sth * oy;
        float w2m = ox * ox + oy * oy;
        float wp2 = w2m - vdw * vdw;
        float w4 = w2m * w2m;
        float butter = 1.f + w4 * w4 * wc8i;
        float Dr = (sp + tau_m * wp2) * butter;
        float Di = (s_m * vdw - bet) * butter;
        float inv = dc_m / (Dr * Dr + Di * Di);
        float Tr = Dr * inv, Ti = -Di * inv;
        Zs[m_ * 97 + wo] = make_float2(zr * Tr - zi * Ti, zr * Ti + zi * Tr);
      }
    }
    __syncthreads();
    // Y phase: wave handles one k-group of 16; lanes span w
    {
      int wl = t & 63, kg = t >> 6;
      for (int wi = 0; wi < 2; ++wi) {
        int wo = wl + 64 * wi;
        if (wo < cnt) {
          float2 acc[16];
          #pragma unroll
          for (int j = 0; j < 16; ++j) acc[j] = make_float2(0.f, 0.f);
          for (int m = 0; m < MM; ++m) {
            float2 zv = Zs[m * 97 + wo];
            #pragma unroll
            for (int j = 0; j < 16; ++j) {
              float2 cv = Ct[m * KK + kg * 16 + j];
              acc[j].x += cv.x * zv.x - cv.y * zv.y;
              acc[j].y += cv.x * zv.y + cv.y * zv.x;
            }
          }
          #pragma unroll
          for (int j = 0; j < 16; ++j) {
            int k = kg * 16 + j;
            Yf[((size_t)(b * KK + k) * HH + h) * WF + wbase + wo] = acc[j];
          }
        }
      }
    }
  }
}

// Inverse row real-FFT. pocketfft c2r semantics: the imaginary parts of the
// DC (k=0) and Nyquist (k=192) bins are IGNORED. We must zero them here or
// they cross-talk between the two packed rows (deterministic ~7e-2 error).
__global__ __launch_bounds__(256) void k6_irowfft(const cfloat* __restrict__ Yf,
                                                  const float2* __restrict__ twg,
                                                  float* __restrict__ out) {
  __shared__ float zre[4][384], zim[4][384];
  __shared__ float2 twl[384];
  int wv = threadIdx.x >> 6, lane = threadIdx.x & 63;
  for (int i = threadIdx.x; i < 384; i += 256) twl[i] = twg[i];
  int pairIdx = blockIdx.x * 4 + wv;
  int bk = pairIdx / 192, p = pairIdx % 192;
  const cfloat* inA = Yf + ((size_t)bk * HH + 2 * p) * WF;
  const cfloat* inB = inA + WF;
  #pragma unroll
  for (int j = 0; j < 4; ++j) {
    int k = lane + 64 * j;
    if (k < WF) {
      float2 a = inA[k], bv = inB[k];
      float ay = (k == 0 || k == 192) ? 0.f : a.y;
      float by = (k == 0 || k == 192) ? 0.f : bv.y;
      zre[wv][k] = a.x - by;
      zim[wv][k] = ay + bv.x;
      if (k >= 1 && k <= 191) {
        zre[wv][384 - k] = a.x + by;
        zim[wv][384 - k] = bv.x - ay;
      }
    }
  }
  __syncthreads();
  float ar[6], ai[6];
  #pragma unroll
  for (int n1 = 0; n1 < 6; ++n1) {
    ar[n1] = zre[wv][6 * lane + n1];
    ai[n1] = zim[wv][6 * lane + n1];
  }
  fft384_regs<1>(ar, ai, lane, twl);
  int k2 = bitrev6(lane);
  const float sc = 1.0f / 384.0f;
  #pragma unroll
  for (int k1 = 0; k1 < 6; ++k1) {
    zre[wv][k2 + 64 * k1] = ar[k1] * sc;
    zim[wv][k2 + 64 * k1] = ai[k1] * sc;
  }
  __syncthreads();
  float* oA = out + ((size_t)bk * HH + 2 * p) * WW;
  float* oB = oA + WW;
  #pragma unroll
  for (int i = 0; i < 6; ++i) {
    int n = lane + 64 * i;
    oA[n] = zre[wv][n];
    oB[n] = zim[wv][n];
  }
}

extern "C" void kernel_launch(void* const* d_in, const int* in_sizes, int n_in,
                              void* d_out, int out_size, void* d_ws, size_t ws_size,
                              hipStream_t stream) {
  const float* x         = (const float*)d_in[0];
  const float* theta     = (const float*)d_in[1];
  const float* B_re      = (const float*)d_in[2];
  const float* B_im      = (const float*)d_in[3];
  const float* C_re      = (const float*)d_in[4];
  const float* C_im      = (const float*)d_in[5];
  const float* alpha_raw = (const float*)d_in[6];
  const float* beta      = (const float*)d_in[7];
  const float* log_dc    = (const float*)d_in[8];
  const float* log_tau   = (const float*)d_in[9];
  const float* log_scale = (const float*)d_in[10];
  const float* log_bw    = (const float*)d_in[11];
  float* out = (float*)d_out;

  char* ws = (char*)d_ws;
  float* sums = (float*)ws;                       // 16 floats
  float2* tw  = (float2*)(ws + 256);              // 384 float2 = 3 KB
  cfloat* S1  = (cfloat*)(ws + 4096);
  cfloat* Yf  = (cfloat*)(ws + 4096 + (size_t)BB * CIN * HH * WF * sizeof(cfloat));

  hipLaunchKernelGGL(k_tw, dim3(6), dim3(64), 0, stream, tw);
  hipLaunchKernelGGL(k0_zero, dim3(1), dim3(64), 0, stream, sums);
  hipLaunchKernelGGL(k1_reduce, dim3(1024), dim3(256), 0, stream, x, sums);
  hipLaunchKernelGGL(k2_rowfft, dim3(6144), dim3(256), 0, stream, x, sums, tw, S1);
  hipLaunchKernelGGL((k3_colfft<-1>), dim3(BB * CIN * 25), dim3(512), 0, stream, S1, tw, 1.0f);
  hipLaunchKernelGGL(k4_mix, dim3(BB * HH), dim3(256), 0, stream, S1, Yf,
                     theta, B_re, B_im, C_re, C_im, alpha_raw, beta,
                     log_dc, log_tau, log_scale, log_bw);
  hipLaunchKernelGGL((k3_colfft<1>), dim3(BB * KK * 25), dim3(512), 0, stream, Yf, tw,
                     1.0f / 384.0f);
  hipLaunchKernelGGL(k6_irowfft, dim3(24576), dim3(256), 0, stream, Yf, tw, out);
}